// Round 10
// baseline (405.808 us; speedup 1.0000x reference)
//
#include <hip/hip_runtime.h>

#define N_NODES 20000
#define E_EDGES 320000
#define E2 (E_EDGES + N_NODES)
#define HID 256
#define SLOPE 0.2f

typedef __bf16 bf16x8 __attribute__((ext_vector_type(8)));
typedef float  f32x4  __attribute__((ext_vector_type(4)));
typedef unsigned int uint4v __attribute__((ext_vector_type(4)));

__device__ __forceinline__ unsigned short f2bf(float f) {   // RNE truncate to bf16
    unsigned b = __float_as_uint(f);
    return (unsigned short)((b + 0x7FFFu + ((b >> 16) & 1u)) >> 16);
}
__device__ __forceinline__ float bf2f(unsigned short h) {
    return __uint_as_float(((unsigned)h) << 16);
}
__device__ __forceinline__ bf16x8 ld_frag(const unsigned short* p) {  // 16B aligned
    uint4v u = *reinterpret_cast<const uint4v*>(p);
    return __builtin_bit_cast(bf16x8, u);
}
#define MFMA16(a, b, c) __builtin_amdgcn_mfma_f32_16x16x32_bf16((a), (b), (c), 0, 0, 0)

// ---------------------------------------------------------------- CSR build
__global__ __launch_bounds__(256) void k_init(int* __restrict__ deg, int* __restrict__ cursor) {
    int i = blockIdx.x * 256 + threadIdx.x;
    if (i < N_NODES) { deg[i] = 1; cursor[i] = 0; }   // deg starts at 1: self loop
}

__global__ __launch_bounds__(256) void k_degree(const int* __restrict__ dst, int* __restrict__ deg) {
    int e = blockIdx.x * 256 + threadIdx.x;
    if (e < E_EDGES) atomicAdd(&deg[dst[e]], 1);
}

// single-block exclusive scan over deg[N] -> off[N+1]; shfl-based wave scan
__global__ __launch_bounds__(1024) void k_scan(const int* __restrict__ deg, int* __restrict__ off) {
    __shared__ int wsum[16];
    const int tid  = threadIdx.x;
    const int wave = tid >> 6;
    const int lane = tid & 63;
    int carry = 0;
    for (int base = 0; base < N_NODES; base += 1024) {
        const int i = base + tid;
        const int v = (i < N_NODES) ? deg[i] : 0;
        int x = v;
        #pragma unroll
        for (int o = 1; o < 64; o <<= 1) {
            int t = __shfl_up(x, o);
            if (lane >= o) x += t;
        }
        if (lane == 63) wsum[wave] = x;
        __syncthreads();
        if (wave == 0 && lane < 16) {
            int y = wsum[lane];
            #pragma unroll
            for (int o = 1; o < 16; o <<= 1) {
                int t = __shfl_up(y, o);
                if (lane >= o) y += t;
            }
            wsum[lane] = y;
        }
        __syncthreads();
        const int wbase = (wave == 0) ? 0 : wsum[wave - 1];
        if (i < N_NODES) off[i] = carry + wbase + (x - v);   // exclusive
        carry += wsum[15];
        __syncthreads();
    }
    if (tid == 0) off[N_NODES] = carry;   // == E2
}

__global__ __launch_bounds__(256) void k_fill(const int* __restrict__ srcA, const int* __restrict__ dstA,
                                              const int* __restrict__ off, int* __restrict__ cursor,
                                              int* __restrict__ csr_src) {
    int e = blockIdx.x * 256 + threadIdx.x;
    if (e >= E2) return;
    int s, d;
    if (e < E_EDGES) { s = srcA[e]; d = dstA[e]; }
    else             { s = d = e - E_EDGES; }        // self loop
    int pos = atomicAdd(&cursor[d], 1);
    csr_src[off[d] + pos] = s;
}

// ---------------------------------------------------------------- fp32 -> bf16 hi/lo split
__global__ __launch_bounds__(256) void k_cvt_x(const float* __restrict__ X,
                                               unsigned short* __restrict__ hi,
                                               unsigned short* __restrict__ lo) {
    const int i = blockIdx.x * 256 + threadIdx.x;      // float4 index
    if (i >= N_NODES * HID / 4) return;
    float4 v = ((const float4*)X)[i];
    ushort4 h, l;
    h.x = f2bf(v.x); l.x = f2bf(v.x - bf2f(h.x));
    h.y = f2bf(v.y); l.y = f2bf(v.y - bf2f(h.y));
    h.z = f2bf(v.z); l.z = f2bf(v.z - bf2f(h.z));
    h.w = f2bf(v.w); l.w = f2bf(v.w - bf2f(h.w));
    ((ushort4*)hi)[i] = h;
    ((ushort4*)lo)[i] = l;
}

// W[k][n] fp32 -> Wt[n][k] bf16 hi/lo. grid (4 Ws, 16 k-chunks), 256 threads (=n).
__global__ __launch_bounds__(256) void k_cvt_w(const float* __restrict__ W0, const float* __restrict__ W1,
                                               const float* __restrict__ W2, const float* __restrict__ W3,
                                               unsigned short* __restrict__ wt_hi,
                                               unsigned short* __restrict__ wt_lo) {
    const float* W = (blockIdx.x == 0) ? W0 : (blockIdx.x == 1) ? W1 : (blockIdx.x == 2) ? W2 : W3;
    unsigned short* oh = wt_hi + (size_t)blockIdx.x * 65536;
    unsigned short* ol = wt_lo + (size_t)blockIdx.x * 65536;
    const int n = threadIdx.x;
    const int k0 = blockIdx.y * 16;
    for (int k = k0; k < k0 + 16; ++k) {
        float v = W[(size_t)k * 256 + n];
        unsigned short h = f2bf(v);
        oh[(size_t)n * 256 + k] = h;
        ol[(size_t)n * 256 + k] = f2bf(v - bf2f(h));
    }
}

// ---------------------------------------------------------------- MFMA GEMM (split bf16)
// C = X @ W + b for Wl and Wr, fp32-accurate via 3-term split:
//   D += Ahi*Bhi + Ahi*Blo + Alo*Bhi   (lo*lo dropped, ~2^-18 rel)
// A: Xhi/Xlo [M][256] bf16 row-major. B: Wt[n][k] bf16 (= W[k][n]).
// mfma_f32_16x16x32_bf16 layouts (m89-verified):
//   A: lane holds A[row=l&15][k=8*(l>>4)+j]   B: B[k=8*(l>>4)+j][col=l&15]
//   D: col=l&15, row=4*(l>>4)+reg
// Block: 256 thr = 4 waves; wave w covers rows m0+w*32..+31 (2 rowtiles),
// 64 cols (4 coltiles): acc[2][4]. No LDS, no barriers; operands are L2-hot.
// grid (157, 8): by<4 -> Wl col-group, else Wr.
__global__ __launch_bounds__(256) void k_gemm_mfma(
        const unsigned short* __restrict__ Ahi, const unsigned short* __restrict__ Alo,
        const unsigned short* __restrict__ WhiL, const unsigned short* __restrict__ WloL,
        const unsigned short* __restrict__ WhiR, const unsigned short* __restrict__ WloR,
        const float* __restrict__ bl, const float* __restrict__ br,
        float* __restrict__ xl, float* __restrict__ xr) {
    const int tid  = threadIdx.x;
    const int lane = tid & 63;
    const int wave = tid >> 6;                       // 0..3
    const int m0   = blockIdx.x * 128 + wave * 32;
    const int by   = blockIdx.y;
    const unsigned short* Whi = (by < 4) ? WhiL : WhiR;
    const unsigned short* Wlo = (by < 4) ? WloL : WloR;
    const float* bias = (by < 4) ? bl : br;
    float*       C    = (by < 4) ? xl : xr;
    const int n0 = (by & 3) * 64;

    const int lrow = lane & 15;
    const int lkb  = lane >> 4;                      // 0..3
    int ar0 = m0 + lrow;       ar0 = (ar0 < N_NODES) ? ar0 : N_NODES - 1;  // clamp OOB reads
    int ar1 = m0 + 16 + lrow;  ar1 = (ar1 < N_NODES) ? ar1 : N_NODES - 1;
    const size_t aoff0 = (size_t)ar0 * HID + lkb * 8;
    const size_t aoff1 = (size_t)ar1 * HID + lkb * 8;

    f32x4 acc[2][4];
    #pragma unroll
    for (int i = 0; i < 2; ++i)
        #pragma unroll
        for (int j = 0; j < 4; ++j)
            acc[i][j] = (f32x4){0.f, 0.f, 0.f, 0.f};

    for (int k0 = 0; k0 < 256; k0 += 32) {
        const bf16x8 a0h = ld_frag(Ahi + aoff0 + k0);
        const bf16x8 a0l = ld_frag(Alo + aoff0 + k0);
        const bf16x8 a1h = ld_frag(Ahi + aoff1 + k0);
        const bf16x8 a1l = ld_frag(Alo + aoff1 + k0);
        #pragma unroll
        for (int ct = 0; ct < 4; ++ct) {
            const size_t boff = (size_t)(n0 + ct * 16 + lrow) * HID + k0 + lkb * 8;
            const bf16x8 bh = ld_frag(Whi + boff);
            const bf16x8 bw = ld_frag(Wlo + boff);
            acc[0][ct] = MFMA16(a0h, bh, acc[0][ct]);
            acc[0][ct] = MFMA16(a0h, bw, acc[0][ct]);
            acc[0][ct] = MFMA16(a0l, bh, acc[0][ct]);
            acc[1][ct] = MFMA16(a1h, bh, acc[1][ct]);
            acc[1][ct] = MFMA16(a1h, bw, acc[1][ct]);
            acc[1][ct] = MFMA16(a1l, bh, acc[1][ct]);
        }
    }

    #pragma unroll
    for (int ct = 0; ct < 4; ++ct) {
        const int gcol = n0 + ct * 16 + lrow;
        const float bb = bias[gcol];
        #pragma unroll
        for (int rt = 0; rt < 2; ++rt) {
            #pragma unroll
            for (int j = 0; j < 4; ++j) {
                const int grow = m0 + rt * 16 + lkb * 4 + j;
                if (grow < N_NODES)
                    C[(size_t)grow * HID + gcol] = acc[rt][ct][j] + bb;
            }
        }
    }
}

// ---------------------------------------------------------------- fused edge phase
// one 64-lane wave per node: online-softmax over incoming edges, aggregate,
// +bias +relu. FP32OUT: write fp32 (final layer) else bf16 hi/lo (feeds gemm2).
template <bool FP32OUT>
__global__ __launch_bounds__(256) void k_edge(const float* __restrict__ xl, const float* __restrict__ xr,
                                              const float* __restrict__ att,
                                              const int* __restrict__ csr_src, const int* __restrict__ off,
                                              const float* __restrict__ bias,
                                              float* __restrict__ outF,
                                              unsigned short* __restrict__ outHi,
                                              unsigned short* __restrict__ outLo) {
    const int node = (blockIdx.x * 256 + threadIdx.x) >> 6;
    const int l = threadIdx.x & 63;
    if (node >= N_NODES) return;

    const float4 w  = *(const float4*)&att[l * 4];
    const float4 xd = *(const float4*)&xr[(size_t)node * 256 + l * 4];
    const int beg = off[node], end = off[node + 1];   // end > beg (self loop)

    float m = -1e30f, ssum = 0.f;
    float4 acc = make_float4(0.f, 0.f, 0.f, 0.f);

    int j1 = csr_src[beg];
    float4 a_nxt = *(const float4*)&xl[(size_t)j1 * 256 + l * 4];
    int j2 = (beg + 1 < end) ? csr_src[beg + 1] : 0;

    for (int p = beg; p < end; ++p) {
        const float4 a = a_nxt;
        if (p + 1 < end)
            a_nxt = *(const float4*)&xl[(size_t)j2 * 256 + l * 4];
        if (p + 2 < end)
            j2 = csr_src[p + 2];

        float t = 0.f, u;
        u = a.x + xd.x; u = (u > 0.f) ? u : SLOPE * u; t = fmaf(u, w.x, t);
        u = a.y + xd.y; u = (u > 0.f) ? u : SLOPE * u; t = fmaf(u, w.y, t);
        u = a.z + xd.z; u = (u > 0.f) ? u : SLOPE * u; t = fmaf(u, w.z, t);
        u = a.w + xd.w; u = (u > 0.f) ? u : SLOPE * u; t = fmaf(u, w.w, t);
        t += __shfl_xor(t, 1);
        t += __shfl_xor(t, 2);
        t += __shfl_xor(t, 4);
        t += __shfl_xor(t, 8);     // 16-lane head-group dot over 64 channels

        const float nm = fmaxf(m, t);
        const float sc = __expf(m - nm);
        const float wp = __expf(t - nm);
        acc.x = fmaf(acc.x, sc, wp * a.x);
        acc.y = fmaf(acc.y, sc, wp * a.y);
        acc.z = fmaf(acc.z, sc, wp * a.z);
        acc.w = fmaf(acc.w, sc, wp * a.w);
        ssum  = fmaf(ssum, sc, wp);
        m = nm;
    }
    const float inv = 1.0f / ssum;
    const float4 bv = *(const float4*)&bias[l * 4];
    float4 o;
    o.x = fmaxf(fmaf(acc.x, inv, bv.x), 0.f);
    o.y = fmaxf(fmaf(acc.y, inv, bv.y), 0.f);
    o.z = fmaxf(fmaf(acc.z, inv, bv.z), 0.f);
    o.w = fmaxf(fmaf(acc.w, inv, bv.w), 0.f);
    if (FP32OUT) {
        *(float4*)&outF[(size_t)node * 256 + l * 4] = o;
    } else {
        ushort4 h, lo;
        h.x = f2bf(o.x); lo.x = f2bf(o.x - bf2f(h.x));
        h.y = f2bf(o.y); lo.y = f2bf(o.y - bf2f(h.y));
        h.z = f2bf(o.z); lo.z = f2bf(o.z - bf2f(h.z));
        h.w = f2bf(o.w); lo.w = f2bf(o.w - bf2f(h.w));
        *(ushort4*)&outHi[(size_t)node * 256 + l * 4] = h;
        *(ushort4*)&outLo[(size_t)node * 256 + l * 4] = lo;
    }
}

// ---------------------------------------------------------------- launch
extern "C" void kernel_launch(void* const* d_in, const int* in_sizes, int n_in,
                              void* d_out, int out_size, void* d_ws, size_t ws_size,
                              hipStream_t stream) {
    const float* x    = (const float*)d_in[0];
    const int*   ei   = (const int*)d_in[1];
    const float* Wl1  = (const float*)d_in[2];
    const float* bl1  = (const float*)d_in[3];
    const float* Wr1  = (const float*)d_in[4];
    const float* br1  = (const float*)d_in[5];
    const float* att1 = (const float*)d_in[6];
    const float* bias1= (const float*)d_in[7];
    const float* Wl2  = (const float*)d_in[8];
    const float* bl2  = (const float*)d_in[9];
    const float* Wr2  = (const float*)d_in[10];
    const float* br2  = (const float*)d_in[11];
    const float* att2 = (const float*)d_in[12];
    const float* bias2= (const float*)d_in[13];
    float* out = (float*)d_out;

    const int* src = ei;            // edge_index[0]
    const int* dst = ei + E_EDGES;  // edge_index[1]

    char* ws = (char*)d_ws;
    size_t o = 0;
    auto alloc = [&](size_t bytes) -> void* {
        void* p = ws + o;
        o += (bytes + 255) & ~(size_t)255;
        return p;
    };
    float*          xl      = (float*)alloc((size_t)N_NODES * HID * 4);
    float*          xr      = (float*)alloc((size_t)N_NODES * HID * 4);
    unsigned short* bufA_hi = (unsigned short*)alloc((size_t)N_NODES * HID * 2);  // X then H
    unsigned short* bufA_lo = (unsigned short*)alloc((size_t)N_NODES * HID * 2);
    unsigned short* wt_hi   = (unsigned short*)alloc((size_t)4 * 65536 * 2);      // [w][n][k]
    unsigned short* wt_lo   = (unsigned short*)alloc((size_t)4 * 65536 * 2);
    int*            csr_src = (int*)alloc((size_t)E2 * 4);
    int*            off     = (int*)alloc((size_t)(N_NODES + 1) * 4);
    int*            deg     = (int*)alloc((size_t)N_NODES * 4);
    int*            cursor  = (int*)alloc((size_t)N_NODES * 4);
    (void)ws_size; (void)n_in; (void)in_sizes; (void)out_size;

    // CSR build (graph shared by both layers)
    k_init<<<(N_NODES + 255) / 256, 256, 0, stream>>>(deg, cursor);
    k_degree<<<(E_EDGES + 255) / 256, 256, 0, stream>>>(dst, deg);
    k_scan<<<1, 1024, 0, stream>>>(deg, off);
    k_fill<<<(E2 + 255) / 256, 256, 0, stream>>>(src, dst, off, cursor, csr_src);

    // bf16 hi/lo conversions
    k_cvt_w<<<dim3(4, 16), 256, 0, stream>>>(Wl1, Wr1, Wl2, Wr2, wt_hi, wt_lo);
    k_cvt_x<<<(N_NODES * HID / 4 + 255) / 256, 256, 0, stream>>>(x, bufA_hi, bufA_lo);

    dim3 ggrid((N_NODES + 127) / 128, 8);
    const int egrid = (N_NODES * 64 + 255) / 256;

    // ---- layer 1
    k_gemm_mfma<<<ggrid, 256, 0, stream>>>(bufA_hi, bufA_lo,
                                           wt_hi, wt_lo, wt_hi + 65536, wt_lo + 65536,
                                           bl1, br1, xl, xr);
    k_edge<false><<<egrid, 256, 0, stream>>>(xl, xr, att1, csr_src, off, bias1,
                                             nullptr, bufA_hi, bufA_lo);

    // ---- layer 2
    k_gemm_mfma<<<ggrid, 256, 0, stream>>>(bufA_hi, bufA_lo,
                                           wt_hi + 2 * 65536, wt_lo + 2 * 65536,
                                           wt_hi + 3 * 65536, wt_lo + 3 * 65536,
                                           bl2, br2, xl, xr);
    k_edge<true><<<egrid, 256, 0, stream>>>(xl, xr, att2, csr_src, off, bias2,
                                            out, nullptr, nullptr);
}

// Round 11
// 383.349 us; speedup vs baseline: 1.0586x; 1.0586x over previous
//
#include <hip/hip_runtime.h>

#define N_NODES 20000
#define E_EDGES 320000
#define E2 (E_EDGES + N_NODES)
#define HID 256
#define SLOPE 0.2f

typedef __bf16 bf16x8 __attribute__((ext_vector_type(8)));
typedef float  f32x4  __attribute__((ext_vector_type(4)));
typedef unsigned int uint4v __attribute__((ext_vector_type(4)));

__device__ __forceinline__ unsigned short f2bf(float f) {   // RNE truncate to bf16
    unsigned b = __float_as_uint(f);
    return (unsigned short)((b + 0x7FFFu + ((b >> 16) & 1u)) >> 16);
}
__device__ __forceinline__ float bf2f(unsigned short h) {
    return __uint_as_float(((unsigned)h) << 16);
}
__device__ __forceinline__ bf16x8 ld_frag(const unsigned short* p) {  // 16B aligned
    uint4v u = *reinterpret_cast<const uint4v*>(p);
    return __builtin_bit_cast(bf16x8, u);
}
#define MFMA16(a, b, c) __builtin_amdgcn_mfma_f32_16x16x32_bf16((a), (b), (c), 0, 0, 0)

// ---------------------------------------------------------------- CSR build
__global__ __launch_bounds__(256) void k_init(int* __restrict__ deg, int* __restrict__ cursor) {
    int i = blockIdx.x * 256 + threadIdx.x;
    if (i < N_NODES) { deg[i] = 1; cursor[i] = 0; }   // deg starts at 1: self loop
}

__global__ __launch_bounds__(256) void k_degree(const int* __restrict__ dst, int* __restrict__ deg) {
    int e = blockIdx.x * 256 + threadIdx.x;
    if (e < E_EDGES) atomicAdd(&deg[dst[e]], 1);
}

// single-block exclusive scan over deg[N] -> off[N+1]; shfl-based wave scan
__global__ __launch_bounds__(1024) void k_scan(const int* __restrict__ deg, int* __restrict__ off) {
    __shared__ int wsum[16];
    const int tid  = threadIdx.x;
    const int wave = tid >> 6;
    const int lane = tid & 63;
    int carry = 0;
    for (int base = 0; base < N_NODES; base += 1024) {
        const int i = base + tid;
        const int v = (i < N_NODES) ? deg[i] : 0;
        int x = v;
        #pragma unroll
        for (int o = 1; o < 64; o <<= 1) {
            int t = __shfl_up(x, o);
            if (lane >= o) x += t;
        }
        if (lane == 63) wsum[wave] = x;
        __syncthreads();
        if (wave == 0 && lane < 16) {
            int y = wsum[lane];
            #pragma unroll
            for (int o = 1; o < 16; o <<= 1) {
                int t = __shfl_up(y, o);
                if (lane >= o) y += t;
            }
            wsum[lane] = y;
        }
        __syncthreads();
        const int wbase = (wave == 0) ? 0 : wsum[wave - 1];
        if (i < N_NODES) off[i] = carry + wbase + (x - v);   // exclusive
        carry += wsum[15];
        __syncthreads();
    }
    if (tid == 0) off[N_NODES] = carry;   // == E2
}

__global__ __launch_bounds__(256) void k_fill(const int* __restrict__ srcA, const int* __restrict__ dstA,
                                              const int* __restrict__ off, int* __restrict__ cursor,
                                              int* __restrict__ csr_src) {
    int e = blockIdx.x * 256 + threadIdx.x;
    if (e >= E2) return;
    int s, d;
    if (e < E_EDGES) { s = srcA[e]; d = dstA[e]; }
    else             { s = d = e - E_EDGES; }        // self loop
    int pos = atomicAdd(&cursor[d], 1);
    csr_src[off[d] + pos] = s;
}

// ---------------------------------------------------------------- fp32 -> bf16 hi/lo split
__global__ __launch_bounds__(256) void k_cvt_x(const float* __restrict__ X,
                                               unsigned short* __restrict__ hi,
                                               unsigned short* __restrict__ lo) {
    const int i = blockIdx.x * 256 + threadIdx.x;      // float4 index
    if (i >= N_NODES * HID / 4) return;
    float4 v = ((const float4*)X)[i];
    ushort4 h, l;
    h.x = f2bf(v.x); l.x = f2bf(v.x - bf2f(h.x));
    h.y = f2bf(v.y); l.y = f2bf(v.y - bf2f(h.y));
    h.z = f2bf(v.z); l.z = f2bf(v.z - bf2f(h.z));
    h.w = f2bf(v.w); l.w = f2bf(v.w - bf2f(h.w));
    ((ushort4*)hi)[i] = h;
    ((ushort4*)lo)[i] = l;
}

// W[k][n] fp32 -> Wt[n][k] bf16 hi/lo. grid (4 Ws, 16 k-chunks), 256 threads (=n).
__global__ __launch_bounds__(256) void k_cvt_w(const float* __restrict__ W0, const float* __restrict__ W1,
                                               const float* __restrict__ W2, const float* __restrict__ W3,
                                               unsigned short* __restrict__ wt_hi,
                                               unsigned short* __restrict__ wt_lo) {
    const float* W = (blockIdx.x == 0) ? W0 : (blockIdx.x == 1) ? W1 : (blockIdx.x == 2) ? W2 : W3;
    unsigned short* oh = wt_hi + (size_t)blockIdx.x * 65536;
    unsigned short* ol = wt_lo + (size_t)blockIdx.x * 65536;
    const int n = threadIdx.x;
    const int k0 = blockIdx.y * 16;
    for (int k = k0; k < k0 + 16; ++k) {
        float v = W[(size_t)k * 256 + n];
        unsigned short h = f2bf(v);
        oh[(size_t)n * 256 + k] = h;
        ol[(size_t)n * 256 + k] = f2bf(v - bf2f(h));
    }
}

// ---------------------------------------------------------------- MFMA GEMM (split bf16)
// Computes BOTH C_l = X@Wl+bl and C_r = X@Wr+br in one block so each A-fetch
// feeds 2x the MFMAs (r10: FETCH 82MB = A re-read per 64-col group; MfmaUtil
// 7.5% latency-bound). 3-term split: D += Ahi*Bhi + Ahi*Blo + Alo*Bhi.
// A: Xhi/Xlo [M][256] bf16 row-major. B: Wt[n][k] bf16 (= W[k][n]).
// mfma_f32_16x16x32_bf16 layouts (m89-verified):
//   A: lane holds A[row=l&15][k=8*(l>>4)+j]   B: B[k=8*(l>>4)+j][col=l&15]
//   D: col=l&15, row=4*(l>>4)+reg
// Block: 256 thr = 4 waves; wave w rows m0+w*32..+31 (2 rowtiles), 64 cols
// (4 coltiles) for BOTH Ws: acc 2x[2][4]. No LDS/barriers; k-loop fully
// unrolled so the scheduler overlaps next-step loads with MFMAs.
// grid (157, 4): n0 = by*64.
__global__ __launch_bounds__(256) void k_gemm_mfma(
        const unsigned short* __restrict__ Ahi, const unsigned short* __restrict__ Alo,
        const unsigned short* __restrict__ WhiL, const unsigned short* __restrict__ WloL,
        const unsigned short* __restrict__ WhiR, const unsigned short* __restrict__ WloR,
        const float* __restrict__ bl, const float* __restrict__ br,
        float* __restrict__ xl, float* __restrict__ xr) {
    const int tid  = threadIdx.x;
    const int lane = tid & 63;
    const int wave = tid >> 6;                       // 0..3
    const int m0   = blockIdx.x * 128 + wave * 32;
    const int n0   = blockIdx.y * 64;

    const int lrow = lane & 15;
    const int lkb  = lane >> 4;                      // 0..3
    int ar0 = m0 + lrow;       ar0 = (ar0 < N_NODES) ? ar0 : N_NODES - 1;  // clamp OOB reads
    int ar1 = m0 + 16 + lrow;  ar1 = (ar1 < N_NODES) ? ar1 : N_NODES - 1;
    const size_t aoff0 = (size_t)ar0 * HID + lkb * 8;
    const size_t aoff1 = (size_t)ar1 * HID + lkb * 8;

    f32x4 accL[2][4], accR[2][4];
    #pragma unroll
    for (int i = 0; i < 2; ++i)
        #pragma unroll
        for (int j = 0; j < 4; ++j) {
            accL[i][j] = (f32x4){0.f, 0.f, 0.f, 0.f};
            accR[i][j] = (f32x4){0.f, 0.f, 0.f, 0.f};
        }

    #pragma unroll
    for (int k0 = 0; k0 < 256; k0 += 32) {
        const bf16x8 a0h = ld_frag(Ahi + aoff0 + k0);
        const bf16x8 a0l = ld_frag(Alo + aoff0 + k0);
        const bf16x8 a1h = ld_frag(Ahi + aoff1 + k0);
        const bf16x8 a1l = ld_frag(Alo + aoff1 + k0);
        #pragma unroll
        for (int ct = 0; ct < 4; ++ct) {
            const size_t boff = (size_t)(n0 + ct * 16 + lrow) * HID + k0 + lkb * 8;
            const bf16x8 bhL = ld_frag(WhiL + boff);
            const bf16x8 blo = ld_frag(WloL + boff);
            const bf16x8 bhR = ld_frag(WhiR + boff);
            const bf16x8 brl = ld_frag(WloR + boff);
            accL[0][ct] = MFMA16(a0h, bhL, accL[0][ct]);
            accL[0][ct] = MFMA16(a0h, blo, accL[0][ct]);
            accL[0][ct] = MFMA16(a0l, bhL, accL[0][ct]);
            accL[1][ct] = MFMA16(a1h, bhL, accL[1][ct]);
            accL[1][ct] = MFMA16(a1h, blo, accL[1][ct]);
            accL[1][ct] = MFMA16(a1l, bhL, accL[1][ct]);
            accR[0][ct] = MFMA16(a0h, bhR, accR[0][ct]);
            accR[0][ct] = MFMA16(a0h, brl, accR[0][ct]);
            accR[0][ct] = MFMA16(a0l, bhR, accR[0][ct]);
            accR[1][ct] = MFMA16(a1h, bhR, accR[1][ct]);
            accR[1][ct] = MFMA16(a1h, brl, accR[1][ct]);
            accR[1][ct] = MFMA16(a1l, bhR, accR[1][ct]);
        }
    }

    #pragma unroll
    for (int ct = 0; ct < 4; ++ct) {
        const int gcol = n0 + ct * 16 + lrow;
        const float bbl = bl[gcol];
        const float bbr = br[gcol];
        #pragma unroll
        for (int rt = 0; rt < 2; ++rt) {
            #pragma unroll
            for (int j = 0; j < 4; ++j) {
                const int grow = m0 + rt * 16 + lkb * 4 + j;
                if (grow < N_NODES) {
                    xl[(size_t)grow * HID + gcol] = accL[rt][ct][j] + bbl;
                    xr[(size_t)grow * HID + gcol] = accR[rt][ct][j] + bbr;
                }
            }
        }
    }
}

// ---------------------------------------------------------------- fused edge phase
// one 64-lane wave per node: online-softmax over incoming edges, aggregate,
// +bias +relu. FP32OUT: write fp32 (final layer) else bf16 hi/lo (feeds gemm2).
template <bool FP32OUT>
__global__ __launch_bounds__(256) void k_edge(const float* __restrict__ xl, const float* __restrict__ xr,
                                              const float* __restrict__ att,
                                              const int* __restrict__ csr_src, const int* __restrict__ off,
                                              const float* __restrict__ bias,
                                              float* __restrict__ outF,
                                              unsigned short* __restrict__ outHi,
                                              unsigned short* __restrict__ outLo) {
    const int node = (blockIdx.x * 256 + threadIdx.x) >> 6;
    const int l = threadIdx.x & 63;
    if (node >= N_NODES) return;

    const float4 w  = *(const float4*)&att[l * 4];
    const float4 xd = *(const float4*)&xr[(size_t)node * 256 + l * 4];
    const int beg = off[node], end = off[node + 1];   // end > beg (self loop)

    float m = -1e30f, ssum = 0.f;
    float4 acc = make_float4(0.f, 0.f, 0.f, 0.f);

    int j1 = csr_src[beg];
    float4 a_nxt = *(const float4*)&xl[(size_t)j1 * 256 + l * 4];
    int j2 = (beg + 1 < end) ? csr_src[beg + 1] : 0;

    for (int p = beg; p < end; ++p) {
        const float4 a = a_nxt;
        if (p + 1 < end)
            a_nxt = *(const float4*)&xl[(size_t)j2 * 256 + l * 4];
        if (p + 2 < end)
            j2 = csr_src[p + 2];

        float t = 0.f, u;
        u = a.x + xd.x; u = (u > 0.f) ? u : SLOPE * u; t = fmaf(u, w.x, t);
        u = a.y + xd.y; u = (u > 0.f) ? u : SLOPE * u; t = fmaf(u, w.y, t);
        u = a.z + xd.z; u = (u > 0.f) ? u : SLOPE * u; t = fmaf(u, w.z, t);
        u = a.w + xd.w; u = (u > 0.f) ? u : SLOPE * u; t = fmaf(u, w.w, t);
        t += __shfl_xor(t, 1);
        t += __shfl_xor(t, 2);
        t += __shfl_xor(t, 4);
        t += __shfl_xor(t, 8);     // 16-lane head-group dot over 64 channels

        const float nm = fmaxf(m, t);
        const float sc = __expf(m - nm);
        const float wp = __expf(t - nm);
        acc.x = fmaf(acc.x, sc, wp * a.x);
        acc.y = fmaf(acc.y, sc, wp * a.y);
        acc.z = fmaf(acc.z, sc, wp * a.z);
        acc.w = fmaf(acc.w, sc, wp * a.w);
        ssum  = fmaf(ssum, sc, wp);
        m = nm;
    }
    const float inv = 1.0f / ssum;
    const float4 bv = *(const float4*)&bias[l * 4];
    float4 o;
    o.x = fmaxf(fmaf(acc.x, inv, bv.x), 0.f);
    o.y = fmaxf(fmaf(acc.y, inv, bv.y), 0.f);
    o.z = fmaxf(fmaf(acc.z, inv, bv.z), 0.f);
    o.w = fmaxf(fmaf(acc.w, inv, bv.w), 0.f);
    if (FP32OUT) {
        *(float4*)&outF[(size_t)node * 256 + l * 4] = o;
    } else {
        ushort4 h, lo;
        h.x = f2bf(o.x); lo.x = f2bf(o.x - bf2f(h.x));
        h.y = f2bf(o.y); lo.y = f2bf(o.y - bf2f(h.y));
        h.z = f2bf(o.z); lo.z = f2bf(o.z - bf2f(h.z));
        h.w = f2bf(o.w); lo.w = f2bf(o.w - bf2f(h.w));
        *(ushort4*)&outHi[(size_t)node * 256 + l * 4] = h;
        *(ushort4*)&outLo[(size_t)node * 256 + l * 4] = lo;
    }
}

// ---------------------------------------------------------------- launch
extern "C" void kernel_launch(void* const* d_in, const int* in_sizes, int n_in,
                              void* d_out, int out_size, void* d_ws, size_t ws_size,
                              hipStream_t stream) {
    const float* x    = (const float*)d_in[0];
    const int*   ei   = (const int*)d_in[1];
    const float* Wl1  = (const float*)d_in[2];
    const float* bl1  = (const float*)d_in[3];
    const float* Wr1  = (const float*)d_in[4];
    const float* br1  = (const float*)d_in[5];
    const float* att1 = (const float*)d_in[6];
    const float* bias1= (const float*)d_in[7];
    const float* Wl2  = (const float*)d_in[8];
    const float* bl2  = (const float*)d_in[9];
    const float* Wr2  = (const float*)d_in[10];
    const float* br2  = (const float*)d_in[11];
    const float* att2 = (const float*)d_in[12];
    const float* bias2= (const float*)d_in[13];
    float* out = (float*)d_out;

    const int* src = ei;            // edge_index[0]
    const int* dst = ei + E_EDGES;  // edge_index[1]

    char* ws = (char*)d_ws;
    size_t o = 0;
    auto alloc = [&](size_t bytes) -> void* {
        void* p = ws + o;
        o += (bytes + 255) & ~(size_t)255;
        return p;
    };
    float*          xl      = (float*)alloc((size_t)N_NODES * HID * 4);
    float*          xr      = (float*)alloc((size_t)N_NODES * HID * 4);
    unsigned short* bufA_hi = (unsigned short*)alloc((size_t)N_NODES * HID * 2);  // X then H
    unsigned short* bufA_lo = (unsigned short*)alloc((size_t)N_NODES * HID * 2);
    unsigned short* wt_hi   = (unsigned short*)alloc((size_t)4 * 65536 * 2);      // [w][n][k]
    unsigned short* wt_lo   = (unsigned short*)alloc((size_t)4 * 65536 * 2);
    int*            csr_src = (int*)alloc((size_t)E2 * 4);
    int*            off     = (int*)alloc((size_t)(N_NODES + 1) * 4);
    int*            deg     = (int*)alloc((size_t)N_NODES * 4);
    int*            cursor  = (int*)alloc((size_t)N_NODES * 4);
    (void)ws_size; (void)n_in; (void)in_sizes; (void)out_size;

    // CSR build (graph shared by both layers)
    k_init<<<(N_NODES + 255) / 256, 256, 0, stream>>>(deg, cursor);
    k_degree<<<(E_EDGES + 255) / 256, 256, 0, stream>>>(dst, deg);
    k_scan<<<1, 1024, 0, stream>>>(deg, off);
    k_fill<<<(E2 + 255) / 256, 256, 0, stream>>>(src, dst, off, cursor, csr_src);

    // bf16 hi/lo conversions
    k_cvt_w<<<dim3(4, 16), 256, 0, stream>>>(Wl1, Wr1, Wl2, Wr2, wt_hi, wt_lo);
    k_cvt_x<<<(N_NODES * HID / 4 + 255) / 256, 256, 0, stream>>>(x, bufA_hi, bufA_lo);

    dim3 ggrid((N_NODES + 127) / 128, 4);
    const int egrid = (N_NODES * 64 + 255) / 256;

    // ---- layer 1
    k_gemm_mfma<<<ggrid, 256, 0, stream>>>(bufA_hi, bufA_lo,
                                           wt_hi, wt_lo, wt_hi + 65536, wt_lo + 65536,
                                           bl1, br1, xl, xr);
    k_edge<false><<<egrid, 256, 0, stream>>>(xl, xr, att1, csr_src, off, bias1,
                                             nullptr, bufA_hi, bufA_lo);

    // ---- layer 2
    k_gemm_mfma<<<ggrid, 256, 0, stream>>>(bufA_hi, bufA_lo,
                                           wt_hi + 2 * 65536, wt_lo + 2 * 65536,
                                           wt_hi + 3 * 65536, wt_lo + 3 * 65536,
                                           bl2, br2, xl, xr);
    k_edge<true><<<egrid, 256, 0, stream>>>(xl, xr, att2, csr_src, off, bias2,
                                            out, nullptr, nullptr);
}